// Round 1
// baseline (1410.243 us; speedup 1.0000x reference)
//
#include <hip/hip_runtime.h>
#include <cstdint>
#include <cstddef>

#define NB 16
#define NC 256
#define NK 8
#define NN 16384
#define NSTAGE 10
#define FKAPPA 20.0f

// ---------------------------------------------------------------------------
// init: broadcast mu_in [C*K] -> mu_cur [B][C][K]
__global__ __launch_bounds__(256) void k_init_mu(const float* __restrict__ mu_in,
                                                 float* __restrict__ mu_cur) {
    int i = blockIdx.x * 256 + threadIdx.x;      // 0 .. NB*NC*NK-1 = 32767
    mu_cur[i] = mu_in[i & (NC * NK - 1)];
}

// ---------------------------------------------------------------------------
// Stage phase A: z[b,n,k] = softmax_k(kappa * sum_c x[b,c,n]*mu[b,c,k])
// and colsum[b,k] += sum_n z[b,n,k]  (colsum pre-zeroed)
// grid: NB*16 blocks (16 n-tiles of 1024), 256 threads, 4 points/thread
__global__ __launch_bounds__(256) void k_assign(const float* __restrict__ x,
                                                const float* __restrict__ mu,
                                                float* __restrict__ z,
                                                float* __restrict__ colsum) {
    const int b  = blockIdx.x >> 4;
    const int nt = blockIdx.x & 15;
    const int t  = threadIdx.x;

    __shared__ float smu[NC * NK];
    for (int i = t; i < NC * NK; i += 256) smu[i] = mu[b * NC * NK + i];
    __syncthreads();

    const int n0 = nt * 1024 + t * 4;
    const float* xp = x + (size_t)b * NC * NN + n0;

    float acc[4][NK];
    #pragma unroll
    for (int i = 0; i < 4; i++)
        #pragma unroll
        for (int k = 0; k < NK; k++) acc[i][k] = 0.f;

    #pragma unroll 4
    for (int c = 0; c < NC; c++) {
        const float4 xv = *reinterpret_cast<const float4*>(xp + (size_t)c * NN);
        const float4 m0 = *reinterpret_cast<const float4*>(&smu[c * NK]);
        const float4 m1 = *reinterpret_cast<const float4*>(&smu[c * NK + 4]);
        const float xs0 = xv.x, xs1 = xv.y, xs2 = xv.z, xs3 = xv.w;
        acc[0][0] += xs0 * m0.x; acc[0][1] += xs0 * m0.y; acc[0][2] += xs0 * m0.z; acc[0][3] += xs0 * m0.w;
        acc[0][4] += xs0 * m1.x; acc[0][5] += xs0 * m1.y; acc[0][6] += xs0 * m1.z; acc[0][7] += xs0 * m1.w;
        acc[1][0] += xs1 * m0.x; acc[1][1] += xs1 * m0.y; acc[1][2] += xs1 * m0.z; acc[1][3] += xs1 * m0.w;
        acc[1][4] += xs1 * m1.x; acc[1][5] += xs1 * m1.y; acc[1][6] += xs1 * m1.z; acc[1][7] += xs1 * m1.w;
        acc[2][0] += xs2 * m0.x; acc[2][1] += xs2 * m0.y; acc[2][2] += xs2 * m0.z; acc[2][3] += xs2 * m0.w;
        acc[2][4] += xs2 * m1.x; acc[2][5] += xs2 * m1.y; acc[2][6] += xs2 * m1.z; acc[2][7] += xs2 * m1.w;
        acc[3][0] += xs3 * m0.x; acc[3][1] += xs3 * m0.y; acc[3][2] += xs3 * m0.z; acc[3][3] += xs3 * m0.w;
        acc[3][4] += xs3 * m1.x; acc[3][5] += xs3 * m1.y; acc[3][6] += xs3 * m1.z; acc[3][7] += xs3 * m1.w;
    }

    float csum[NK];
    #pragma unroll
    for (int k = 0; k < NK; k++) csum[k] = 0.f;

    float* zp = z + ((size_t)b * NN + n0) * NK;
    #pragma unroll
    for (int i = 0; i < 4; i++) {
        float l[NK];
        float m = -1e30f;
        #pragma unroll
        for (int k = 0; k < NK; k++) { l[k] = FKAPPA * acc[i][k]; m = fmaxf(m, l[k]); }
        float s = 0.f;
        #pragma unroll
        for (int k = 0; k < NK; k++) { l[k] = __expf(l[k] - m); s += l[k]; }
        const float inv = 1.f / s;
        #pragma unroll
        for (int k = 0; k < NK; k++) { l[k] *= inv; csum[k] += l[k]; }
        *reinterpret_cast<float4*>(zp + i * NK)     = make_float4(l[0], l[1], l[2], l[3]);
        *reinterpret_cast<float4*>(zp + i * NK + 4) = make_float4(l[4], l[5], l[6], l[7]);
    }

    // block-reduce csum over 256 threads, then atomicAdd
    #pragma unroll
    for (int off = 32; off > 0; off >>= 1)
        #pragma unroll
        for (int k = 0; k < NK; k++) csum[k] += __shfl_down(csum[k], off, 64);

    __shared__ float red[4][NK];
    const int wave = t >> 6, lane = t & 63;
    if (lane == 0)
        #pragma unroll
        for (int k = 0; k < NK; k++) red[wave][k] = csum[k];
    __syncthreads();
    if (t < NK) {
        float s = red[0][t] + red[1][t] + red[2][t] + red[3][t];
        atomicAdd(&colsum[b * NK + t], s);
    }
}

// ---------------------------------------------------------------------------
// Stage phase B: mu_out[b,c,k] = (1/(1e-6+colsum[b,k])) * sum_n x[b,c,n]*z[b,n,k]
// grid: NB*32 blocks (c-tiles of 8), 256 threads, 4 points/thread per iter
__global__ __launch_bounds__(256) void k_update(const float* __restrict__ x,
                                                const float* __restrict__ z,
                                                const float* __restrict__ colsum,
                                                float* __restrict__ mu_out) {
    const int b  = blockIdx.x >> 5;
    const int ct = blockIdx.x & 31;
    const int c0 = ct * 8;
    const int t  = threadIdx.x;

    const float* xp = x + (size_t)b * NC * NN;
    const float* zp = z + (size_t)b * NN * NK;

    float acc[8][NK];
    #pragma unroll
    for (int ci = 0; ci < 8; ci++)
        #pragma unroll
        for (int k = 0; k < NK; k++) acc[ci][k] = 0.f;

    for (int it = 0; it < NN / 1024; ++it) {
        const int n0 = it * 1024 + t * 4;
        float zv[4][NK];
        #pragma unroll
        for (int i = 0; i < 4; i++) {
            const float4 z0 = *reinterpret_cast<const float4*>(zp + (size_t)(n0 + i) * NK);
            const float4 z1 = *reinterpret_cast<const float4*>(zp + (size_t)(n0 + i) * NK + 4);
            zv[i][0] = z0.x; zv[i][1] = z0.y; zv[i][2] = z0.z; zv[i][3] = z0.w;
            zv[i][4] = z1.x; zv[i][5] = z1.y; zv[i][6] = z1.z; zv[i][7] = z1.w;
        }
        #pragma unroll
        for (int ci = 0; ci < 8; ci++) {
            const float4 xv = *reinterpret_cast<const float4*>(xp + (size_t)(c0 + ci) * NN + n0);
            const float xs[4] = {xv.x, xv.y, xv.z, xv.w};
            #pragma unroll
            for (int i = 0; i < 4; i++)
                #pragma unroll
                for (int k = 0; k < NK; k++) acc[ci][k] += xs[i] * zv[i][k];
        }
    }

    // block reduce 64 accumulators over 256 threads
    #pragma unroll
    for (int off = 32; off > 0; off >>= 1)
        #pragma unroll
        for (int ci = 0; ci < 8; ci++)
            #pragma unroll
            for (int k = 0; k < NK; k++) acc[ci][k] += __shfl_down(acc[ci][k], off, 64);

    __shared__ float red[4][64];
    const int wave = t >> 6, lane = t & 63;
    if (lane == 0) {
        #pragma unroll
        for (int ci = 0; ci < 8; ci++)
            #pragma unroll
            for (int k = 0; k < NK; k++) red[wave][ci * NK + k] = acc[ci][k];
    }
    __syncthreads();
    if (t < 64) {
        const float s = red[0][t] + red[1][t] + red[2][t] + red[3][t];
        const int ci = t >> 3, k = t & 7;
        const float inv = 1.f / (1e-6f + colsum[b * NK + k]);
        mu_out[(size_t)b * NC * NK + (size_t)(c0 + ci) * NK + k] = s * inv;
    }
}

// ---------------------------------------------------------------------------
// Stage phase C: l2-normalize mu over c.  grid: NB blocks, 256 threads (t = c)
__global__ __launch_bounds__(256) void k_l2norm(const float* __restrict__ mu_in,
                                                float* __restrict__ mu_out) {
    const int b = blockIdx.x;
    const int t = threadIdx.x;
    const float4 v0 = *reinterpret_cast<const float4*>(mu_in + (size_t)b * NC * NK + t * NK);
    const float4 v1 = *reinterpret_cast<const float4*>(mu_in + (size_t)b * NC * NK + t * NK + 4);
    float v[NK] = {v0.x, v0.y, v0.z, v0.w, v1.x, v1.y, v1.z, v1.w};

    float sq[NK];
    #pragma unroll
    for (int k = 0; k < NK; k++) sq[k] = v[k] * v[k];
    #pragma unroll
    for (int off = 32; off > 0; off >>= 1)
        #pragma unroll
        for (int k = 0; k < NK; k++) sq[k] += __shfl_down(sq[k], off, 64);

    __shared__ float red[4][NK];
    const int wave = t >> 6, lane = t & 63;
    if (lane == 0)
        #pragma unroll
        for (int k = 0; k < NK; k++) red[wave][k] = sq[k];
    __syncthreads();
    __shared__ float scale[NK];
    if (t < NK) {
        const float tot = red[0][t] + red[1][t] + red[2][t] + red[3][t];
        scale[t] = 1.f / (1e-6f + sqrtf(tot));
    }
    __syncthreads();
    #pragma unroll
    for (int k = 0; k < NK; k++) v[k] *= scale[k];
    *reinterpret_cast<float4*>(mu_out + (size_t)b * NC * NK + t * NK)     = make_float4(v[0], v[1], v[2], v[3]);
    *reinterpret_cast<float4*>(mu_out + (size_t)b * NC * NK + t * NK + 4) = make_float4(v[4], v[5], v[6], v[7]);
}

// ---------------------------------------------------------------------------
// finalize: out0[b,k,c] = mu[b,c,k]   (32768 elems)
__global__ __launch_bounds__(256) void k_write_mu(const float* __restrict__ mu,
                                                  float* __restrict__ out) {
    const int i = blockIdx.x * 256 + threadIdx.x;
    const int b = i >> 11, r = i & 2047;
    const int k = r >> 8, c = r & 255;
    out[i] = mu[(size_t)b * NC * NK + c * NK + k];
}

// finalize: out1[b,n,k] = z[b,n,k] / (1e-6 + colsum[b,k])   (B*N threads)
__global__ __launch_bounds__(256) void k_write_z(const float* __restrict__ z,
                                                 const float* __restrict__ colsum,
                                                 float* __restrict__ out) {
    const int i = blockIdx.x * 256 + threadIdx.x;   // 0 .. NB*NN-1
    const int b = i >> 14;
    float inv[NK];
    #pragma unroll
    for (int k = 0; k < NK; k++) inv[k] = 1.f / (1e-6f + colsum[b * NK + k]);
    const float4 z0 = *reinterpret_cast<const float4*>(z + (size_t)i * NK);
    const float4 z1 = *reinterpret_cast<const float4*>(z + (size_t)i * NK + 4);
    *reinterpret_cast<float4*>(out + (size_t)i * NK)     = make_float4(z0.x * inv[0], z0.y * inv[1], z0.z * inv[2], z0.w * inv[3]);
    *reinterpret_cast<float4*>(out + (size_t)i * NK + 4) = make_float4(z1.x * inv[4], z1.y * inv[5], z1.z * inv[6], z1.w * inv[7]);
}

// ---------------------------------------------------------------------------
extern "C" void kernel_launch(void* const* d_in, const int* in_sizes, int n_in,
                              void* d_out, int out_size, void* d_ws, size_t ws_size,
                              hipStream_t stream) {
    const float* x     = (const float*)d_in[0];   // [16,256,128,128]
    const float* mu_in = (const float*)d_in[1];   // [1,256,8]
    float* out = (float*)d_out;                   // [16*8*256] mu_f ++ [16*16384*8] z_
    char* ws = (char*)d_ws;

    float* z      = (float*)ws;                                            // 8,388,608 B
    float* colsum = (float*)(ws + (size_t)NB * NN * NK * 4);               // 10*128*4 B
    float* mu_a   = (float*)(ws + (size_t)NB * NN * NK * 4 + 8192);        // 131072 B
    float* mu_b   = (float*)(ws + (size_t)NB * NN * NK * 4 + 8192 + (size_t)NB * NC * NK * 4);

    hipMemsetAsync(colsum, 0, NSTAGE * NB * NK * sizeof(float), stream);
    k_init_mu<<<NB * NC * NK / 256, 256, 0, stream>>>(mu_in, mu_a);

    for (int s = 0; s < NSTAGE; ++s) {
        float* cs = colsum + s * NB * NK;
        k_assign<<<NB * 16, 256, 0, stream>>>(x, mu_a, z, cs);
        k_update<<<NB * 32, 256, 0, stream>>>(x, z, cs, mu_b);
        k_l2norm<<<NB, 256, 0, stream>>>(mu_b, mu_a);
    }

    k_write_mu<<<NB * NK * NC / 256, 256, 0, stream>>>(mu_a, out);
    k_write_z<<<NB * NN / 256, 256, 0, stream>>>(z, colsum + (NSTAGE - 1) * NB * NK,
                                                 out + NB * NK * NC);
}